// Round 15
// baseline (250.924 us; speedup 1.0000x reference)
//
#include <hip/hip_runtime.h>
#include <hip/hip_bf16.h>

// ---------------- problem constants ----------------
#define B_TOTAL   32768
#define L_SITES   256
#define N_MID     254        // L-2 middle sites
#define HALF_PI_F 1.57079632679489662f
#define EPS_NORM  1e-8f

// ---------------- ws layout (float/dword slots) ----------------
// [WS_FRAG .. +520191]  A-operand fragment table: 254 steps x 8 frags x 64 lanes x 4 dwords
//                       frag q = h*4 + kh*2 + p  (h: c-half, kh: feature, p: 0=hi,1=lo)
//                       contraction axis PI-PERMUTED (k-slot (quad,j) holds
//                       a = (j<4 ? quad*4+j : 16+quad*4+j-4)) so the swapped-MFMA
//                       output feeds the next step with no transpose.
// [WS_C0   .. +63]      core0 fp32  [f][32]
// [WS_CN   .. +639]     coreN fp32  [f][a][10]
// (x-transpose REMOVED this round: mps reads x directly — r14 proved VMEM
//  has 4x headroom, and per-lane x lines are L1-resident across 32 sites)
#define WS_FRAG 0
#define WS_C0   520192
#define WS_CN   520256

typedef short bf16x8 __attribute__((ext_vector_type(8)));
typedef float f32x4  __attribute__((ext_vector_type(4)));

// pi-permutation of the contraction axis (k-slot -> actual a index)
__device__ __host__ __forceinline__ int pi_perm(int quad, int j) {
    return (j < 4) ? (quad * 4 + j) : (16 + quad * 4 + (j - 4));
}

__device__ __forceinline__ unsigned short f2bf(float f) {
    unsigned u = __builtin_bit_cast(unsigned, f);
    u += 0x7FFFu + ((u >> 16) & 1u);          // RNE
    return (unsigned short)(u >> 16);
}
__device__ __forceinline__ float bf2f(unsigned short h) {
    unsigned u = ((unsigned)h) << 16;
    return __builtin_bit_cast(float, u);
}
__device__ __forceinline__ bf16x8 asbf(uint4 u) {
    return __builtin_bit_cast(bf16x8, u);
}
// polynomial sincos for sin(pi/2 x), cos(pi/2 x), x in [0,1].
// Taylor through x^11 / x^12: truncation <= 6e-8. Verified passing r11/r14.
__device__ __forceinline__ void psincos(float x, float* s, float* c) {
    float u = x * x;
    float sp = fmaf(u, -3.5988432352121e-6f, 1.6044118478736e-4f);
    sp = fmaf(u, sp, -4.6817541353187e-3f);
    sp = fmaf(u, sp, 7.9692626246167e-2f);
    sp = fmaf(u, sp, -6.4596409750625e-1f);
    sp = fmaf(u, sp, 1.5707963267949f);
    *s = x * sp;
    float cp = fmaf(u, 4.7108749076366e-7f, -2.5202042373061e-5f);
    cp = fmaf(u, cp, 9.1926027483943e-4f);
    cp = fmaf(u, cp, -2.0863480763353e-2f);
    cp = fmaf(u, cp, 2.5366950790105e-1f);
    cp = fmaf(u, cp, -1.2337005501362f);
    *c = fmaf(u, cp, 1.0f);
}
// packed RNE f32x2 -> bf16x2 (lowers to v_cvt_pk_bf16_f32)
__device__ __forceinline__ unsigned pkbf2(float a, float b) {
    float2 p; p.x = a; p.y = b;
    __hip_bfloat162 h2 = __float22bfloat162_rn(p);
    unsigned u;
    __builtin_memcpy(&u, &h2, 4);
    return u;                                  // a in bits 0..15, b in 16..31
}
// split 8 fp32 into hi/lo bf16 fragments via packed cvt (RNE, proven)
__device__ __forceinline__ void split8(const float* v, bf16x8& hi, bf16x8& lo) {
    uint4 H, L;
    unsigned* hp = (unsigned*)&H;
    unsigned* lp = (unsigned*)&L;
    #pragma unroll
    for (int d = 0; d < 4; ++d) {
        float a = v[2 * d], b = v[2 * d + 1];
        unsigned hb = pkbf2(a, b);
        float h0 = __builtin_bit_cast(float, hb << 16);
        float h1 = __builtin_bit_cast(float, hb & 0xFFFF0000u);
        hp[d] = hb;
        lp[d] = pkbf2(a - h0, b - h1);         // exact residuals
    }
    hi = __builtin_bit_cast(bf16x8, H);
    lo = __builtin_bit_cast(bf16x8, L);
}
// per-wave input-dtype flag: x in [0,1) -> bf16 halves always < 0x4000
__device__ __forceinline__ bool detect_bf16(const unsigned* x_raw, int lane) {
    unsigned v = x_raw[lane];
    return __ballot((v & 0xFFFFu) >= 0x4000u) == 0ull;
}
// direct x read: x[b][site] (uniform branch on bf, per-lane b)
__device__ __forceinline__ float ldx(bool bf, const void* x, int b, int site) {
    if (bf) return bf2f(((const unsigned short*)x)[(size_t)b * L_SITES + site]);
    return ((const float*)x)[(size_t)b * L_SITES + site];
}

// ---------------- slim aux kernel (transpose DELETED) ----------------
// blocks [0, N_MID) : fragment builder, one block per site (r7-proven path:
//                     stage site's 8KB core pair coalesced in LDS, emit
//                     pi-permuted hi/lo split dwords).
// block  N_MID      : small cores -> fp32 (C0, CN).
__global__ __launch_bounds__(256)
void aux_all(const void* __restrict__ x_in, const void* __restrict__ c0_in,
             const void* __restrict__ am_in, const void* __restrict__ cn_in,
             float* __restrict__ ws) {
    const int lane = threadIdx.x & 63;
    const bool bf = detect_bf16((const unsigned*)x_in, lane);
    const int b = blockIdx.x;

    if (b < N_MID) {
        const int t = b;
        __shared__ float amS[2][32][33];        // [f][a][m], +1 pad vs 4-way conflicts
        if (!bf) {
            const float* src = (const float*)am_in + (size_t)t * 2048;
            for (int idx = threadIdx.x; idx < 2048; idx += 256) {
                amS[idx >> 10][(idx >> 5) & 31][idx & 31] = src[idx];
            }
        } else {
            const unsigned short* src = (const unsigned short*)am_in + (size_t)t * 2048;
            for (int idx = threadIdx.x; idx < 2048; idx += 256) {
                amS[idx >> 10][(idx >> 5) & 31][idx & 31] = bf2f(src[idx]);
            }
        }
        __syncthreads();
        #pragma unroll
        for (int u = 0; u < 2; ++u) {
            const int oi = threadIdx.x + 256 * u;   // 0..511
            const int q  = oi >> 6;                 // frag 0..7
            const int l  = oi & 63;                 // lane
            const int h  = q >> 2;
            const int kh = (q >> 1) & 1;
            const int p  = q & 1;
            const int m  = h * 16 + (l & 15);
            const int kb = (l >> 4) * 8;
            unsigned dw[4];
            #pragma unroll
            for (int d = 0; d < 4; ++d) {
                unsigned e01[2];
                #pragma unroll
                for (int s = 0; s < 2; ++s) {
                    int k = kb + 2 * d + s;         // k-slot 0..31
                    int a = pi_perm(k >> 3, k & 7); // PI-permuted contraction index
                    float v = amS[kh][a][m];
                    unsigned short hi = f2bf(v);
                    e01[s] = (p == 0) ? hi : f2bf(v - bf2f(hi));
                }
                dw[d] = e01[0] | (e01[1] << 16);
            }
            uint4 o; o.x = dw[0]; o.y = dw[1]; o.z = dw[2]; o.w = dw[3];
            ((uint4*)ws)[(size_t)(t * 8 + q) * 64 + l] = o;
        }
    } else {
        for (int i = threadIdx.x; i < 640; i += 256) {
            if (i < 64)
                ws[WS_C0 + i] = bf ? bf2f(((const unsigned short*)c0_in)[i])
                                   : ((const float*)c0_in)[i];
            ws[WS_CN + i] = bf ? bf2f(((const unsigned short*)cn_in)[i])
                               : ((const float*)cn_in)[i];
        }
    }
}

// ---------------- main chain kernel ----------------
// r11/r14 verified math. THIS ROUND (after r14 falsified VMEM-throughput and
// r7->r11 falsified VALU-count as bottlenecks — every variant lands at
// ~170us):
//  * 12 INDEPENDENT depth-1 MFMAs (12 separate accumulators, VALU-summed
//    (a+b)+c then post-scale combine) instead of 4x 3-deep accumulate
//    chains — removes 2 dependent-MFMA result-latency links from the
//    loop-carried path. Costs ~48 VALU/step (proven free headroom).
//  * direct x reads (transpose deleted from aux): per-lane line is
//    L1-resident across a 32-site window; VMEM has 4x headroom (r14).
//  * plain C++ frag loads (r9-r12 proved asm prefetch corrupts; r14 proved
//    staging doesn't help — let the compiler place them).
__global__ __launch_bounds__(256, 2)
void mps_mfma(const float* __restrict__ ws, const void* __restrict__ x_in,
              void* __restrict__ out) {
    const int lane = threadIdx.x & 63;
    const int w    = threadIdx.x >> 6;
    const int r    = lane & 15;
    const int quad = lane >> 4;
    const int b0   = (blockIdx.x * 4 + w) * 16;
    const uint4* __restrict__ BF = (const uint4*)ws;   // WS_FRAG = 0
    const int i = b0 + r;
    const bool bf = detect_bf16((const unsigned*)x_in, lane);

    // ---- M0 in pi-layout: mm[j] = M0[b=r][a=pi(quad,j)] ----
    float mm[8];
    {
        float x0 = ldx(bf, x_in, i, 0);
        float sn, cs; psincos(x0, &sn, &cs);
        const float* c0 = ws + WS_C0;
        #pragma unroll
        for (int j = 0; j < 8; ++j) {
            int a = pi_perm(quad, j);
            mm[j] = cs * c0[a] + sn * c0[32 + a];
        }
    }
    float ct, st;                                  // factors for step 0 (site 1)
    { float xc = ldx(bf, x_in, i, 1); psincos(xc, &st, &ct); }
    float xn = ldx(bf, x_in, i, 2);                // x for step-1 factors

    #pragma unroll 1
    for (int t = 0; t < N_MID; ++t) {
        const uint4* F = BF + (size_t)t * 512 + lane;
        uint4 f0 = F[0];    uint4 f1 = F[64];
        uint4 f2 = F[128];  uint4 f3 = F[192];
        uint4 f4 = F[256];  uint4 f5 = F[320];
        uint4 f6 = F[384];  uint4 f7 = F[448];

        float ctn, stn; psincos(xn, &stn, &ctn);   // factors for step t+1
        int xr = t + 3; if (xr > 255) xr = 255;    // site for step t+2 factors
        float xn2 = ldx(bf, x_in, i, xr);

        // split M once; 12 INDEPENDENT MFMAs (depth 1); VALU-sum; post-scale.
        bf16x8 mh, ml;
        split8(mm, mh, ml);
        const f32x4 z = {0.f, 0.f, 0.f, 0.f};
        __builtin_amdgcn_s_setprio(1);
        f32x4 a00 = __builtin_amdgcn_mfma_f32_16x16x32_bf16(asbf(f0), mh, z, 0, 0, 0);
        f32x4 a01 = __builtin_amdgcn_mfma_f32_16x16x32_bf16(asbf(f2), mh, z, 0, 0, 0);
        f32x4 a10 = __builtin_amdgcn_mfma_f32_16x16x32_bf16(asbf(f4), mh, z, 0, 0, 0);
        f32x4 a11 = __builtin_amdgcn_mfma_f32_16x16x32_bf16(asbf(f6), mh, z, 0, 0, 0);
        f32x4 b00 = __builtin_amdgcn_mfma_f32_16x16x32_bf16(asbf(f1), mh, z, 0, 0, 0);
        f32x4 b01 = __builtin_amdgcn_mfma_f32_16x16x32_bf16(asbf(f3), mh, z, 0, 0, 0);
        f32x4 b10 = __builtin_amdgcn_mfma_f32_16x16x32_bf16(asbf(f5), mh, z, 0, 0, 0);
        f32x4 b11 = __builtin_amdgcn_mfma_f32_16x16x32_bf16(asbf(f7), mh, z, 0, 0, 0);
        f32x4 c00 = __builtin_amdgcn_mfma_f32_16x16x32_bf16(asbf(f0), ml, z, 0, 0, 0);
        f32x4 c01 = __builtin_amdgcn_mfma_f32_16x16x32_bf16(asbf(f2), ml, z, 0, 0, 0);
        f32x4 c10 = __builtin_amdgcn_mfma_f32_16x16x32_bf16(asbf(f4), ml, z, 0, 0, 0);
        f32x4 c11 = __builtin_amdgcn_mfma_f32_16x16x32_bf16(asbf(f6), ml, z, 0, 0, 0);
        __builtin_amdgcn_s_setprio(0);
        #pragma unroll
        for (int j = 0; j < 4; ++j) {
            float p00 = (a00[j] + b00[j]) + c00[j];
            float p01 = (a01[j] + b01[j]) + c01[j];
            float p10 = (a10[j] + b10[j]) + c10[j];
            float p11 = (a11[j] + b11[j]) + c11[j];
            mm[j]     = fmaf(st, p01, ct * p00);
            mm[4 + j] = fmaf(st, p11, ct * p10);
        }

        // normalize every 8th step + final (scale cancels in between)
        if (((t & 7) == 7) || (t == N_MID - 1)) {
            float ss = 0.f;
            #pragma unroll
            for (int j = 0; j < 8; ++j) ss = fmaf(mm[j], mm[j], ss);
            ss += __shfl_xor(ss, 16);
            ss += __shfl_xor(ss, 32);
            float kk = 1.0f / (sqrtf(ss) + EPS_NORM);
            #pragma unroll
            for (int j = 0; j < 8; ++j) mm[j] *= kk;
        }

        ct = ctn; st = stn; xn = xn2;
    }

    // ---- readout: logits[r][c] = sum_a M[r][a]*(cN*KN0[a,c] + sN*KN1[a,c]) ----
    {
        float xN = ldx(bf, x_in, i, L_SITES - 1);
        float sN, cN; psincos(xN, &sN, &cN);
        const float* kn = ws + WS_CN;        // [f][a][10]
        float acc[10];
        #pragma unroll
        for (int c = 0; c < 10; ++c) acc[c] = 0.f;
        #pragma unroll
        for (int j = 0; j < 8; ++j) {
            int a = pi_perm(quad, j);
            float Ma = mm[j];
            #pragma unroll
            for (int c = 0; c < 10; ++c) {
                float fin = cN * kn[a * 10 + c] + sN * kn[320 + a * 10 + c];
                acc[c] = fmaf(Ma, fin, acc[c]);
            }
        }
        #pragma unroll
        for (int c = 0; c < 10; ++c) {
            acc[c] += __shfl_xor(acc[c], 16);
            acc[c] += __shfl_xor(acc[c], 32);
        }
        if (quad == 0) {
            if (bf) {
                __hip_bfloat16* o = (__hip_bfloat16*)out;
                #pragma unroll
                for (int c = 0; c < 10; ++c)
                    o[(size_t)(b0 + r) * 10 + c] = __float2bfloat16(acc[c]);
            } else {
                float* o = (float*)out;
                #pragma unroll
                for (int c = 0; c < 10; ++c)
                    o[(size_t)(b0 + r) * 10 + c] = acc[c];
            }
        }
    }
}

// ---------------- launch ----------------
extern "C" void kernel_launch(void* const* d_in, const int* in_sizes, int n_in,
                              void* d_out, int out_size, void* d_ws, size_t ws_size,
                              hipStream_t stream) {
    float* ws = (float*)d_ws;
    aux_all<<<N_MID + 1, 256, 0, stream>>>(d_in[0], d_in[1], d_in[2], d_in[3], ws);
    // 512 blocks x 4 waves x 16 samples = 32768 samples; 2048 waves = 2 waves/SIMD
    mps_mfma<<<512, 256, 0, stream>>>(ws, d_in[0], d_out);
}

// Round 16
// 219.762 us; speedup vs baseline: 1.1418x; 1.1418x over previous
//
#include <hip/hip_runtime.h>
#include <hip/hip_bf16.h>

// ---------------- problem constants ----------------
#define B_TOTAL   32768
#define L_SITES   256
#define N_MID     254        // L-2 middle sites
#define HALF_PI_F 1.57079632679489662f
#define EPS_NORM  1e-8f

// ---------------- ws layout (float/dword slots) ----------------
// [WS_FRAG .. +520191]  A-operand fragment table: 254 steps x 8 frags x 64 lanes x 4 dwords
//                       frag q = h*4 + kh*2 + p  (h: c-half, kh: feature, p: 0=hi,1=lo)
//                       contraction axis PI-PERMUTED (k-slot (quad,j) holds
//                       a = (j<4 ? quad*4+j : 16+quad*4+j-4)) so the swapped-MFMA
//                       output feeds the next step with no transpose.
// [WS_C0   .. +63]      core0 fp32  [f][32]
// [WS_CN   .. +639]     coreN fp32  [f][a][10]
// (x-transpose removed for good: mps stages its 64 sample-rows into LDS once,
//  coalesced — in-loop x reads are conflict-free LDS broadcasts, zero VMEM)
#define WS_FRAG 0
#define WS_C0   520192
#define WS_CN   520256

typedef short bf16x8 __attribute__((ext_vector_type(8)));
typedef float f32x4  __attribute__((ext_vector_type(4)));

// pi-permutation of the contraction axis (k-slot -> actual a index)
__device__ __host__ __forceinline__ int pi_perm(int quad, int j) {
    return (j < 4) ? (quad * 4 + j) : (16 + quad * 4 + (j - 4));
}

__device__ __forceinline__ unsigned short f2bf(float f) {
    unsigned u = __builtin_bit_cast(unsigned, f);
    u += 0x7FFFu + ((u >> 16) & 1u);          // RNE
    return (unsigned short)(u >> 16);
}
__device__ __forceinline__ float bf2f(unsigned short h) {
    unsigned u = ((unsigned)h) << 16;
    return __builtin_bit_cast(float, u);
}
__device__ __forceinline__ bf16x8 asbf(uint4 u) {
    return __builtin_bit_cast(bf16x8, u);
}
// polynomial sincos for sin(pi/2 x), cos(pi/2 x), x in [0,1].
// Taylor through x^11 / x^12: truncation <= 6e-8. Verified passing r11/r14/r15.
__device__ __forceinline__ void psincos(float x, float* s, float* c) {
    float u = x * x;
    float sp = fmaf(u, -3.5988432352121e-6f, 1.6044118478736e-4f);
    sp = fmaf(u, sp, -4.6817541353187e-3f);
    sp = fmaf(u, sp, 7.9692626246167e-2f);
    sp = fmaf(u, sp, -6.4596409750625e-1f);
    sp = fmaf(u, sp, 1.5707963267949f);
    *s = x * sp;
    float cp = fmaf(u, 4.7108749076366e-7f, -2.5202042373061e-5f);
    cp = fmaf(u, cp, 9.1926027483943e-4f);
    cp = fmaf(u, cp, -2.0863480763353e-2f);
    cp = fmaf(u, cp, 2.5366950790105e-1f);
    cp = fmaf(u, cp, -1.2337005501362f);
    *c = fmaf(u, cp, 1.0f);
}
// packed RNE f32x2 -> bf16x2 (lowers to v_cvt_pk_bf16_f32)
__device__ __forceinline__ unsigned pkbf2(float a, float b) {
    float2 p; p.x = a; p.y = b;
    __hip_bfloat162 h2 = __float22bfloat162_rn(p);
    unsigned u;
    __builtin_memcpy(&u, &h2, 4);
    return u;                                  // a in bits 0..15, b in 16..31
}
// split 8 fp32 into hi/lo bf16 fragments via packed cvt (RNE, proven)
__device__ __forceinline__ void split8(const float* v, bf16x8& hi, bf16x8& lo) {
    uint4 H, L;
    unsigned* hp = (unsigned*)&H;
    unsigned* lp = (unsigned*)&L;
    #pragma unroll
    for (int d = 0; d < 4; ++d) {
        float a = v[2 * d], b = v[2 * d + 1];
        unsigned hb = pkbf2(a, b);
        float h0 = __builtin_bit_cast(float, hb << 16);
        float h1 = __builtin_bit_cast(float, hb & 0xFFFF0000u);
        hp[d] = hb;
        lp[d] = pkbf2(a - h0, b - h1);         // exact residuals
    }
    hi = __builtin_bit_cast(bf16x8, H);
    lo = __builtin_bit_cast(bf16x8, L);
}
// per-wave input-dtype flag: x in [0,1) -> bf16 halves always < 0x4000
__device__ __forceinline__ bool detect_bf16(const unsigned* x_raw, int lane) {
    unsigned v = x_raw[lane];
    return __ballot((v & 0xFFFFu) >= 0x4000u) == 0ull;
}

// ---------------- slim aux kernel ----------------
// blocks [0, 2*N_MID) : fragment builder, TWO blocks per site (b = 2t+kh):
//                       each stages one 4KB feature matrix [32][32] coalesced
//                       in LDS and emits the 4 frags (h,p) for that kh.
//                       (r15's one-block-per-site was latency-bound: 255
//                       blocks, 1/CU, ~35us for 4MB — split doubles the
//                       parallelism and halves per-block serial work.)
// block  2*N_MID      : small cores -> fp32 (C0, CN).
__global__ __launch_bounds__(256)
void aux_all(const void* __restrict__ x_in, const void* __restrict__ c0_in,
             const void* __restrict__ am_in, const void* __restrict__ cn_in,
             float* __restrict__ ws) {
    const int lane = threadIdx.x & 63;
    const bool bf = detect_bf16((const unsigned*)x_in, lane);
    const int b = blockIdx.x;

    if (b < 2 * N_MID) {
        const int t  = b >> 1;
        const int kh = b & 1;
        __shared__ float amS[32][33];           // [a][m], +1 pad
        if (!bf) {
            const float* src = (const float*)am_in + (size_t)t * 2048 + kh * 1024;
            for (int idx = threadIdx.x; idx < 1024; idx += 256)
                amS[idx >> 5][idx & 31] = src[idx];
        } else {
            const unsigned short* src =
                (const unsigned short*)am_in + (size_t)t * 2048 + kh * 1024;
            for (int idx = threadIdx.x; idx < 1024; idx += 256)
                amS[idx >> 5][idx & 31] = bf2f(src[idx]);
        }
        __syncthreads();
        const int l  = threadIdx.x & 63;        // lane
        const int qi = threadIdx.x >> 6;        // 0..3
        const int h  = qi >> 1;
        const int p  = qi & 1;
        const int q  = h * 4 + kh * 2 + p;      // frag index
        const int m  = h * 16 + (l & 15);
        const int kb = (l >> 4) * 8;
        unsigned dw[4];
        #pragma unroll
        for (int d = 0; d < 4; ++d) {
            unsigned e01[2];
            #pragma unroll
            for (int s = 0; s < 2; ++s) {
                int k = kb + 2 * d + s;         // k-slot 0..31
                int a = pi_perm(k >> 3, k & 7); // PI-permuted contraction index
                float v = amS[a][m];
                unsigned short hi = f2bf(v);
                e01[s] = (p == 0) ? hi : f2bf(v - bf2f(hi));
            }
            dw[d] = e01[0] | (e01[1] << 16);
        }
        uint4 o; o.x = dw[0]; o.y = dw[1]; o.z = dw[2]; o.w = dw[3];
        ((uint4*)ws)[(size_t)(t * 8 + q) * 64 + l] = o;
    } else {
        for (int i = threadIdx.x; i < 640; i += 256) {
            if (i < 64)
                ws[WS_C0 + i] = bf ? bf2f(((const unsigned short*)c0_in)[i])
                                   : ((const float*)c0_in)[i];
            ws[WS_CN + i] = bf ? bf2f(((const unsigned short*)cn_in)[i])
                               : ((const float*)cn_in)[i];
        }
    }
}

// ---------------- main chain kernel ----------------
// Verified r11/r14 step math (swapped-operand chain, post-scale factorization,
// 4 independent 3-deep MFMA chains, psincos, norm cadence). THIS ROUND:
//  * per-block LDS x-stage: block owns 64 consecutive samples; stage
//    x[bb..bb+63][0..255] coalesced into xs[site][b_local] (64KB; 2 blocks/CU
//    fits 160KB LDS, occupancy unchanged at 2 waves/SIMD). In-loop x reads
//    become conflict-free LDS broadcasts (16 banks x quad-broadcast) — the
//    64MB global transpose AND r15's pathological strided loads (+46us, one
//    30ms outlier dispatch) are both gone.
//  * plain C++ frag loads (asm prefetch corrupts: r9-r12; staging null: r14).
__global__ __launch_bounds__(256, 2)
void mps_mfma(const float* __restrict__ ws, const void* __restrict__ x_in,
              void* __restrict__ out) {
    __shared__ float xs[L_SITES][64];           // [site][b_local] = 64KB
    const int lane = threadIdx.x & 63;
    const int w    = threadIdx.x >> 6;
    const int r    = lane & 15;
    const int quad = lane >> 4;
    const int bb   = blockIdx.x * 64;           // block's first sample
    const int bl   = w * 16 + r;                // b_local of this thread
    const int b0   = bb + w * 16;
    const uint4* __restrict__ BF = (const uint4*)ws;   // WS_FRAG = 0
    const bool bf = detect_bf16((const unsigned*)x_in, lane);

    // ---- stage x rows (coalesced): thread (row=tid>>2, q=tid&3) ----
    if (!bf) {
        const float4* x4 = (const float4*)x_in;       // row = 64 float4
        const int row = threadIdx.x >> 2;
        const int q   = threadIdx.x & 3;
        #pragma unroll
        for (int u = 0; u < 16; ++u) {
            int c4 = q + u * 4;                       // 0..63
            float4 v = x4[(size_t)(bb + row) * (L_SITES / 4) + c4];
            xs[c4 * 4 + 0][row] = v.x;
            xs[c4 * 4 + 1][row] = v.y;
            xs[c4 * 4 + 2][row] = v.z;
            xs[c4 * 4 + 3][row] = v.w;
        }
    } else {
        const uint4* x8 = (const uint4*)x_in;         // row = 32 uint4 (8 bf16)
        const int row = threadIdx.x >> 2;
        const int q   = threadIdx.x & 3;
        #pragma unroll
        for (int u = 0; u < 8; ++u) {
            int c8 = q + u * 4;                       // 0..31
            uint4 v = x8[(size_t)(bb + row) * (L_SITES / 8) + c8];
            const unsigned short* e = (const unsigned short*)&v;
            #pragma unroll
            for (int k = 0; k < 8; ++k) xs[c8 * 8 + k][row] = bf2f(e[k]);
        }
    }
    __syncthreads();

    // ---- M0 in pi-layout: mm[j] = M0[b][a=pi(quad,j)] ----
    float mm[8];
    {
        float x0 = xs[0][bl];
        float sn, cs; psincos(x0, &sn, &cs);
        const float* c0 = ws + WS_C0;
        #pragma unroll
        for (int j = 0; j < 8; ++j) {
            int a = pi_perm(quad, j);
            mm[j] = cs * c0[a] + sn * c0[32 + a];
        }
    }
    float ct, st;                                  // factors for step 0 (site 1)
    psincos(xs[1][bl], &st, &ct);
    float xn = xs[2][bl];                          // x for step-1 factors

    #pragma unroll 1
    for (int t = 0; t < N_MID; ++t) {
        const uint4* F = BF + (size_t)t * 512 + lane;
        uint4 f0 = F[0];    uint4 f1 = F[64];
        uint4 f2 = F[128];  uint4 f3 = F[192];
        uint4 f4 = F[256];  uint4 f5 = F[320];
        uint4 f6 = F[384];  uint4 f7 = F[448];

        float ctn, stn; psincos(xn, &stn, &ctn);   // factors for step t+1
        int xr = t + 3; if (xr > 255) xr = 255;    // site for step t+2 factors
        float xn2 = xs[xr][bl];

        // split M once; 12 MFMA as 4 independent 3-deep chains; post-scale.
        bf16x8 mh, ml;
        split8(mm, mh, ml);
        const f32x4 z = {0.f, 0.f, 0.f, 0.f};
        __builtin_amdgcn_s_setprio(1);
        f32x4 p00 = __builtin_amdgcn_mfma_f32_16x16x32_bf16(asbf(f0), mh, z, 0, 0, 0);
        f32x4 p01 = __builtin_amdgcn_mfma_f32_16x16x32_bf16(asbf(f2), mh, z, 0, 0, 0);
        f32x4 p10 = __builtin_amdgcn_mfma_f32_16x16x32_bf16(asbf(f4), mh, z, 0, 0, 0);
        f32x4 p11 = __builtin_amdgcn_mfma_f32_16x16x32_bf16(asbf(f6), mh, z, 0, 0, 0);
        p00 = __builtin_amdgcn_mfma_f32_16x16x32_bf16(asbf(f1), mh, p00, 0, 0, 0);
        p01 = __builtin_amdgcn_mfma_f32_16x16x32_bf16(asbf(f3), mh, p01, 0, 0, 0);
        p10 = __builtin_amdgcn_mfma_f32_16x16x32_bf16(asbf(f5), mh, p10, 0, 0, 0);
        p11 = __builtin_amdgcn_mfma_f32_16x16x32_bf16(asbf(f7), mh, p11, 0, 0, 0);
        p00 = __builtin_amdgcn_mfma_f32_16x16x32_bf16(asbf(f0), ml, p00, 0, 0, 0);
        p01 = __builtin_amdgcn_mfma_f32_16x16x32_bf16(asbf(f2), ml, p01, 0, 0, 0);
        p10 = __builtin_amdgcn_mfma_f32_16x16x32_bf16(asbf(f4), ml, p10, 0, 0, 0);
        p11 = __builtin_amdgcn_mfma_f32_16x16x32_bf16(asbf(f6), ml, p11, 0, 0, 0);
        __builtin_amdgcn_s_setprio(0);
        #pragma unroll
        for (int j = 0; j < 4; ++j) {
            mm[j]     = fmaf(st, p01[j], ct * p00[j]);
            mm[4 + j] = fmaf(st, p11[j], ct * p10[j]);
        }

        // normalize every 8th step + final (scale cancels in between)
        if (((t & 7) == 7) || (t == N_MID - 1)) {
            float ss = 0.f;
            #pragma unroll
            for (int j = 0; j < 8; ++j) ss = fmaf(mm[j], mm[j], ss);
            ss += __shfl_xor(ss, 16);
            ss += __shfl_xor(ss, 32);
            float kk = 1.0f / (sqrtf(ss) + EPS_NORM);
            #pragma unroll
            for (int j = 0; j < 8; ++j) mm[j] *= kk;
        }

        ct = ctn; st = stn; xn = xn2;
    }

    // ---- readout: logits[r][c] = sum_a M[r][a]*(cN*KN0[a,c] + sN*KN1[a,c]) ----
    {
        float xN = xs[L_SITES - 1][bl];
        float sN, cN; psincos(xN, &sN, &cN);
        const float* kn = ws + WS_CN;        // [f][a][10]
        float acc[10];
        #pragma unroll
        for (int c = 0; c < 10; ++c) acc[c] = 0.f;
        #pragma unroll
        for (int j = 0; j < 8; ++j) {
            int a = pi_perm(quad, j);
            float Ma = mm[j];
            #pragma unroll
            for (int c = 0; c < 10; ++c) {
                float fin = cN * kn[a * 10 + c] + sN * kn[320 + a * 10 + c];
                acc[c] = fmaf(Ma, fin, acc[c]);
            }
        }
        #pragma unroll
        for (int c = 0; c < 10; ++c) {
            acc[c] += __shfl_xor(acc[c], 16);
            acc[c] += __shfl_xor(acc[c], 32);
        }
        if (quad == 0) {
            if (bf) {
                __hip_bfloat16* o = (__hip_bfloat16*)out;
                #pragma unroll
                for (int c = 0; c < 10; ++c)
                    o[(size_t)(b0 + r) * 10 + c] = __float2bfloat16(acc[c]);
            } else {
                float* o = (float*)out;
                #pragma unroll
                for (int c = 0; c < 10; ++c)
                    o[(size_t)(b0 + r) * 10 + c] = acc[c];
            }
        }
    }
}

// ---------------- launch ----------------
extern "C" void kernel_launch(void* const* d_in, const int* in_sizes, int n_in,
                              void* d_out, int out_size, void* d_ws, size_t ws_size,
                              hipStream_t stream) {
    float* ws = (float*)d_ws;
    aux_all<<<2 * N_MID + 1, 256, 0, stream>>>(d_in[0], d_in[1], d_in[2], d_in[3], ws);
    // 512 blocks x 4 waves x 16 samples = 32768 samples; 2048 waves = 2 waves/SIMD
    mps_mfma<<<512, 256, 0, stream>>>(ws, d_in[0], d_out);
}

// Round 17
// 216.298 us; speedup vs baseline: 1.1601x; 1.0160x over previous
//
#include <hip/hip_runtime.h>
#include <hip/hip_bf16.h>

// ---------------- problem constants ----------------
#define B_TOTAL   32768
#define L_SITES   256
#define N_MID     254        // L-2 middle sites
#define HALF_PI_F 1.57079632679489662f
#define EPS_NORM  1e-8f

// ---------------- ws layout (float/dword slots) ----------------
// [WS_FRAG .. +520191]  A-operand fragment table: 254 steps x 8 frags x 64 lanes x 4 dwords
//                       frag q = h*4 + kh*2 + p  (h: c-half, kh: feature, p: 0=hi,1=lo)
//                       contraction axis PI-PERMUTED (k-slot (quad,j) holds
//                       a = (j<4 ? quad*4+j : 16+quad*4+j-4)) so the swapped-MFMA
//                       output feeds the next step with no transpose.
// [WS_C0   .. +63]      core0 fp32  [f][32]
// [WS_CN   .. +639]     coreN fp32  [f][a][10]
#define WS_FRAG 0
#define WS_C0   520192
#define WS_CN   520256

typedef short bf16x8 __attribute__((ext_vector_type(8)));
typedef float f32x4  __attribute__((ext_vector_type(4)));

// pi-permutation of the contraction axis (k-slot -> actual a index)
__device__ __host__ __forceinline__ int pi_perm(int quad, int j) {
    return (j < 4) ? (quad * 4 + j) : (16 + quad * 4 + (j - 4));
}

__device__ __forceinline__ unsigned short f2bf(float f) {
    unsigned u = __builtin_bit_cast(unsigned, f);
    u += 0x7FFFu + ((u >> 16) & 1u);          // RNE
    return (unsigned short)(u >> 16);
}
__device__ __forceinline__ float bf2f(unsigned short h) {
    unsigned u = ((unsigned)h) << 16;
    return __builtin_bit_cast(float, u);
}
__device__ __forceinline__ bf16x8 asbf(uint4 u) {
    return __builtin_bit_cast(bf16x8, u);
}
// polynomial sincos for sin(pi/2 x), cos(pi/2 x), x in [0,1].
// Taylor through x^11 / x^12: truncation <= 6e-8. Verified r11/r14/r16.
__device__ __forceinline__ void psincos(float x, float* s, float* c) {
    float u = x * x;
    float sp = fmaf(u, -3.5988432352121e-6f, 1.6044118478736e-4f);
    sp = fmaf(u, sp, -4.6817541353187e-3f);
    sp = fmaf(u, sp, 7.9692626246167e-2f);
    sp = fmaf(u, sp, -6.4596409750625e-1f);
    sp = fmaf(u, sp, 1.5707963267949f);
    *s = x * sp;
    float cp = fmaf(u, 4.7108749076366e-7f, -2.5202042373061e-5f);
    cp = fmaf(u, cp, 9.1926027483943e-4f);
    cp = fmaf(u, cp, -2.0863480763353e-2f);
    cp = fmaf(u, cp, 2.5366950790105e-1f);
    cp = fmaf(u, cp, -1.2337005501362f);
    *c = fmaf(u, cp, 1.0f);
}
// packed RNE f32x2 -> bf16x2 (lowers to v_cvt_pk_bf16_f32)
__device__ __forceinline__ unsigned pkbf2(float a, float b) {
    float2 p; p.x = a; p.y = b;
    __hip_bfloat162 h2 = __float22bfloat162_rn(p);
    unsigned u;
    __builtin_memcpy(&u, &h2, 4);
    return u;                                  // a in bits 0..15, b in 16..31
}
// split 8 fp32 into hi/lo bf16 fragments via packed cvt (RNE, proven)
__device__ __forceinline__ void split8(const float* v, bf16x8& hi, bf16x8& lo) {
    uint4 H, L;
    unsigned* hp = (unsigned*)&H;
    unsigned* lp = (unsigned*)&L;
    #pragma unroll
    for (int d = 0; d < 4; ++d) {
        float a = v[2 * d], b = v[2 * d + 1];
        unsigned hb = pkbf2(a, b);
        float h0 = __builtin_bit_cast(float, hb << 16);
        float h1 = __builtin_bit_cast(float, hb & 0xFFFF0000u);
        hp[d] = hb;
        lp[d] = pkbf2(a - h0, b - h1);         // exact residuals
    }
    hi = __builtin_bit_cast(bf16x8, H);
    lo = __builtin_bit_cast(bf16x8, L);
}
// per-wave input-dtype flag: x in [0,1) -> bf16 halves always < 0x4000
__device__ __forceinline__ bool detect_bf16(const unsigned* x_raw, int lane) {
    unsigned v = x_raw[lane];
    return __ballot((v & 0xFFFFu) >= 0x4000u) == 0ull;
}

// ---------------- slim aux kernel (r16, verified) ----------------
// blocks [0, 2*N_MID) : fragment builder, two blocks per site (b = 2t+kh)
// block  2*N_MID      : small cores -> fp32 (C0, CN)
__global__ __launch_bounds__(256)
void aux_all(const void* __restrict__ x_in, const void* __restrict__ c0_in,
             const void* __restrict__ am_in, const void* __restrict__ cn_in,
             float* __restrict__ ws) {
    const int lane = threadIdx.x & 63;
    const bool bf = detect_bf16((const unsigned*)x_in, lane);
    const int b = blockIdx.x;

    if (b < 2 * N_MID) {
        const int t  = b >> 1;
        const int kh = b & 1;
        __shared__ float amS[32][33];           // [a][m], +1 pad
        if (!bf) {
            const float* src = (const float*)am_in + (size_t)t * 2048 + kh * 1024;
            for (int idx = threadIdx.x; idx < 1024; idx += 256)
                amS[idx >> 5][idx & 31] = src[idx];
        } else {
            const unsigned short* src =
                (const unsigned short*)am_in + (size_t)t * 2048 + kh * 1024;
            for (int idx = threadIdx.x; idx < 1024; idx += 256)
                amS[idx >> 5][idx & 31] = bf2f(src[idx]);
        }
        __syncthreads();
        const int l  = threadIdx.x & 63;        // lane
        const int qi = threadIdx.x >> 6;        // 0..3
        const int h  = qi >> 1;
        const int p  = qi & 1;
        const int q  = h * 4 + kh * 2 + p;      // frag index
        const int m  = h * 16 + (l & 15);
        const int kb = (l >> 4) * 8;
        unsigned dw[4];
        #pragma unroll
        for (int d = 0; d < 4; ++d) {
            unsigned e01[2];
            #pragma unroll
            for (int s = 0; s < 2; ++s) {
                int k = kb + 2 * d + s;         // k-slot 0..31
                int a = pi_perm(k >> 3, k & 7); // PI-permuted contraction index
                float v = amS[a][m];
                unsigned short hi = f2bf(v);
                e01[s] = (p == 0) ? hi : f2bf(v - bf2f(hi));
            }
            dw[d] = e01[0] | (e01[1] << 16);
        }
        uint4 o; o.x = dw[0]; o.y = dw[1]; o.z = dw[2]; o.w = dw[3];
        ((uint4*)ws)[(size_t)(t * 8 + q) * 64 + l] = o;
    } else {
        for (int i = threadIdx.x; i < 640; i += 256) {
            if (i < 64)
                ws[WS_C0 + i] = bf ? bf2f(((const unsigned short*)c0_in)[i])
                                   : ((const float*)c0_in)[i];
            ws[WS_CN + i] = bf ? bf2f(((const unsigned short*)cn_in)[i])
                               : ((const float*)cn_in)[i];
        }
    }
}

// ---------------- main chain kernel ----------------
// Verified r16 math + LDS x-stage. THIS ROUND: occupancy-truth scheduling.
// Diagnosis: iter t+1's frag loads REUSE iter t's f0..f7 registers, so they
// can only issue after t's last MFMA -> ~300cyc L2 latency lands on the
// loop-carried path. Every round the compiler SANK the loads (VGPR 56-92
// despite 16 declared uint4s) because the AMDGPU scheduler minimizes pressure
// targeting 4-8 waves/EU occupancy — but our grid structurally supplies only
// 2 waves/EU. amdgpu_waves_per_eu(2,2) pins min=max=2: the scheduler now
// knows the true occupancy, gets a 256-VGPR budget, and can keep the
// 2x-unrolled ping-pong buffers (fa*/fb*, plain C++ loads — compiler-visible,
// correct waitcnt/spills by construction) genuinely co-live.
__global__ __launch_bounds__(256)
__attribute__((amdgpu_waves_per_eu(2, 2)))
void mps_mfma(const float* __restrict__ ws, const void* __restrict__ x_in,
              void* __restrict__ out) {
    __shared__ float xs[L_SITES][64];           // [site][b_local] = 64KB
    const int lane = threadIdx.x & 63;
    const int w    = threadIdx.x >> 6;
    const int r    = lane & 15;
    const int quad = lane >> 4;
    const int bb   = blockIdx.x * 64;           // block's first sample
    const int bl   = w * 16 + r;                // b_local of this thread
    const int b0   = bb + w * 16;
    const uint4* __restrict__ BF = (const uint4*)ws;   // WS_FRAG = 0
    const bool bf = detect_bf16((const unsigned*)x_in, lane);

    // ---- stage x rows (coalesced) into xs[site][b_local] ----
    if (!bf) {
        const float4* x4 = (const float4*)x_in;       // row = 64 float4
        const int row = threadIdx.x >> 2;
        const int q   = threadIdx.x & 3;
        #pragma unroll
        for (int u = 0; u < 16; ++u) {
            int c4 = q + u * 4;                       // 0..63
            float4 v = x4[(size_t)(bb + row) * (L_SITES / 4) + c4];
            xs[c4 * 4 + 0][row] = v.x;
            xs[c4 * 4 + 1][row] = v.y;
            xs[c4 * 4 + 2][row] = v.z;
            xs[c4 * 4 + 3][row] = v.w;
        }
    } else {
        const uint4* x8 = (const uint4*)x_in;         // row = 32 uint4 (8 bf16)
        const int row = threadIdx.x >> 2;
        const int q   = threadIdx.x & 3;
        #pragma unroll
        for (int u = 0; u < 8; ++u) {
            int c8 = q + u * 4;                       // 0..31
            uint4 v = x8[(size_t)(bb + row) * (L_SITES / 8) + c8];
            const unsigned short* e = (const unsigned short*)&v;
            #pragma unroll
            for (int k = 0; k < 8; ++k) xs[c8 * 8 + k][row] = bf2f(e[k]);
        }
    }
    __syncthreads();

// load one frag batch into 8 NAMED uint4s (plain loads, compiler-visible)
#define LOADB(A0, A1, A2, A3, A4, A5, A6, A7, STEP)                                \
    {                                                                              \
        const uint4* F_ = BF + (size_t)(STEP) * 512 + lane;                        \
        A0 = F_[0];    A1 = F_[64];   A2 = F_[128];  A3 = F_[192];                 \
        A4 = F_[256];  A5 = F_[320];  A6 = F_[384];  A7 = F_[448];                 \
    }

// one chain step: split M once -> 12 MFMA (4 indep 3-deep chains) -> post-scale
// combine with (CT,ST) -> optional norm.  (bit-identical to r7/r11/r16)
#define DO_STEP(CT, ST, Q0, Q1, Q2, Q3, Q4, Q5, Q6, Q7, DONORM)                    \
    {                                                                              \
        bf16x8 mh, ml;                                                             \
        split8(mm, mh, ml);                                                        \
        const f32x4 z = {0.f, 0.f, 0.f, 0.f};                                      \
        __builtin_amdgcn_s_setprio(1);                                             \
        f32x4 p00 = __builtin_amdgcn_mfma_f32_16x16x32_bf16(asbf(Q0), mh, z, 0, 0, 0);    \
        f32x4 p01 = __builtin_amdgcn_mfma_f32_16x16x32_bf16(asbf(Q2), mh, z, 0, 0, 0);    \
        f32x4 p10 = __builtin_amdgcn_mfma_f32_16x16x32_bf16(asbf(Q4), mh, z, 0, 0, 0);    \
        f32x4 p11 = __builtin_amdgcn_mfma_f32_16x16x32_bf16(asbf(Q6), mh, z, 0, 0, 0);    \
        p00 = __builtin_amdgcn_mfma_f32_16x16x32_bf16(asbf(Q1), mh, p00, 0, 0, 0); \
        p01 = __builtin_amdgcn_mfma_f32_16x16x32_bf16(asbf(Q3), mh, p01, 0, 0, 0); \
        p10 = __builtin_amdgcn_mfma_f32_16x16x32_bf16(asbf(Q5), mh, p10, 0, 0, 0); \
        p11 = __builtin_amdgcn_mfma_f32_16x16x32_bf16(asbf(Q7), mh, p11, 0, 0, 0); \
        p00 = __builtin_amdgcn_mfma_f32_16x16x32_bf16(asbf(Q0), ml, p00, 0, 0, 0); \
        p01 = __builtin_amdgcn_mfma_f32_16x16x32_bf16(asbf(Q2), ml, p01, 0, 0, 0); \
        p10 = __builtin_amdgcn_mfma_f32_16x16x32_bf16(asbf(Q4), ml, p10, 0, 0, 0); \
        p11 = __builtin_amdgcn_mfma_f32_16x16x32_bf16(asbf(Q6), ml, p11, 0, 0, 0); \
        __builtin_amdgcn_s_setprio(0);                                             \
        _Pragma("unroll")                                                          \
        for (int j = 0; j < 4; ++j) {                                              \
            mm[j]     = fmaf((ST), p01[j], (CT) * p00[j]);                         \
            mm[4 + j] = fmaf((ST), p11[j], (CT) * p10[j]);                         \
        }                                                                          \
        if (DONORM) {                                                              \
            float ss = 0.f;                                                        \
            _Pragma("unroll")                                                      \
            for (int j = 0; j < 8; ++j) ss = fmaf(mm[j], mm[j], ss);               \
            ss += __shfl_xor(ss, 16);                                              \
            ss += __shfl_xor(ss, 32);                                              \
            float kk = 1.0f / (sqrtf(ss) + EPS_NORM);                              \
            _Pragma("unroll")                                                      \
            for (int j = 0; j < 8; ++j) mm[j] *= kk;                               \
        }                                                                          \
    }

    // ---- M0 in pi-layout: mm[j] = M0[b][a=pi(quad,j)] ----
    float mm[8];
    {
        float x0 = xs[0][bl];
        float sn, cs; psincos(x0, &sn, &cs);
        const float* c0 = ws + WS_C0;
        #pragma unroll
        for (int j = 0; j < 8; ++j) {
            int a = pi_perm(quad, j);
            mm[j] = cs * c0[a] + sn * c0[32 + a];
        }
    }
    float ct0, st0;                                 // factors for step 0 (site 1)
    psincos(xs[1][bl], &st0, &ct0);
    float x1 = xs[2][bl];                           // x for step-1 factors

    uint4 fa0, fa1, fa2, fa3, fa4, fa5, fa6, fa7;
    uint4 fb0, fb1, fb2, fb3, fb4, fb5, fb6, fb7;
    LOADB(fa0, fa1, fa2, fa3, fa4, fa5, fa6, fa7, 0)

    #pragma unroll 1
    for (int t = 0; t < N_MID; t += 2) {
        // ======== even step t: consume FA; prefetch FB for t+1 ========
        LOADB(fb0, fb1, fb2, fb3, fb4, fb5, fb6, fb7, t + 1)   // t+1 <= 253
        float x2 = xs[t + 3][bl];                   // x for step t+2 (site t+3 <= 255)
        float ct1, st1; psincos(x1, &st1, &ct1);    // factors for step t+1
        DO_STEP(ct0, st0, fa0, fa1, fa2, fa3, fa4, fa5, fa6, fa7, false)

        // ======== odd step t+1: consume FB; prefetch FA for t+2 ========
        LOADB(fa0, fa1, fa2, fa3, fa4, fa5, fa6, fa7, t + 2)   // t=252 -> in-ws garbage, never consumed
        int xr = t + 4; if (xr > 255) xr = 255;
        x1 = xs[xr][bl];                            // x for step t+3
        psincos(x2, &st0, &ct0);                    // factors for step t+2
        DO_STEP(ct1, st1, fb0, fb1, fb2, fb3, fb4, fb5, fb6, fb7,
                (((t + 1) & 7) == 7) || (t + 1 == N_MID - 1))
    }
#undef DO_STEP
#undef LOADB

    // ---- readout: logits[r][c] = sum_a M[r][a]*(cN*KN0[a,c] + sN*KN1[a,c]) ----
    {
        float xN = xs[L_SITES - 1][bl];
        float sN, cN; psincos(xN, &sN, &cN);
        const float* kn = ws + WS_CN;        // [f][a][10]
        float acc[10];
        #pragma unroll
        for (int c = 0; c < 10; ++c) acc[c] = 0.f;
        #pragma unroll
        for (int j = 0; j < 8; ++j) {
            int a = pi_perm(quad, j);
            float Ma = mm[j];
            #pragma unroll
            for (int c = 0; c < 10; ++c) {
                float fin = cN * kn[a * 10 + c] + sN * kn[320 + a * 10 + c];
                acc[c] = fmaf(Ma, fin, acc[c]);
            }
        }
        #pragma unroll
        for (int c = 0; c < 10; ++c) {
            acc[c] += __shfl_xor(acc[c], 16);
            acc[c] += __shfl_xor(acc[c], 32);
        }
        if (quad == 0) {
            if (bf) {
                __hip_bfloat16* o = (__hip_bfloat16*)out;
                #pragma unroll
                for (int c = 0; c < 10; ++c)
                    o[(size_t)(b0 + r) * 10 + c] = __float2bfloat16(acc[c]);
            } else {
                float* o = (float*)out;
                #pragma unroll
                for (int c = 0; c < 10; ++c)
                    o[(size_t)(b0 + r) * 10 + c] = acc[c];
            }
        }
    }
}

// ---------------- launch ----------------
extern "C" void kernel_launch(void* const* d_in, const int* in_sizes, int n_in,
                              void* d_out, int out_size, void* d_ws, size_t ws_size,
                              hipStream_t stream) {
    float* ws = (float*)d_ws;
    aux_all<<<2 * N_MID + 1, 256, 0, stream>>>(d_in[0], d_in[1], d_in[2], d_in[3], ws);
    // 512 blocks x 4 waves x 16 samples = 32768 samples; 2048 waves = 2 waves/SIMD
    mps_mfma<<<512, 256, 0, stream>>>(ws, d_in[0], d_out);
}